// Round 19
// baseline (496.524 us; speedup 1.0000x reference)
//
#include <hip/hip_runtime.h>

#define B_ 2
#define L_ 2048
#define DIM_ 512
#define NH_ 8
#define HD_ 64
#define TOPK_ 512

typedef __attribute__((ext_vector_type(8))) short short8;
typedef __attribute__((ext_vector_type(4))) float f32x4;
typedef unsigned short ushort_t;

__device__ __forceinline__ unsigned f2ord(float f) {
  unsigned u = __float_as_uint(f);
  return (u >> 31) ? ~u : (u | 0x80000000u);
}
__device__ __forceinline__ float ord2f(unsigned k) {
  unsigned u = (k >> 31) ? (k ^ 0x80000000u) : ~k;
  return __uint_as_float(u);
}
// f32 -> bf16 bits, round-to-nearest-even
__device__ __forceinline__ ushort_t bfrne(float f) {
  unsigned u = __float_as_uint(f);
  return (ushort_t)((u + 0x7FFFu + ((u >> 16) & 1u)) >> 16);
}

// ---------------- split f32 -> bf16 hi/lo panels (8 elems/thread) ----------------
__global__ __launch_bounds__(256) void split_k(
    const float* __restrict__ src, ushort_t* __restrict__ dh,
    ushort_t* __restrict__ dl, int n8)
{
  const int i = blockIdx.x * 256 + threadIdx.x;
  if (i >= n8) return;
  const float4 a = ((const float4*)src)[2 * i];
  const float4 b = ((const float4*)src)[2 * i + 1];
  float f[8] = {a.x, a.y, a.z, a.w, b.x, b.y, b.z, b.w};
  short8 h, l;
#pragma unroll
  for (int j = 0; j < 8; ++j) {
    const ushort_t hi = bfrne(f[j]);
    const float hf = __uint_as_float((unsigned)hi << 16);
    h[j] = (short)hi;
    l[j] = (short)bfrne(f[j] - hf);
  }
  *(short8*)(dh + 8 * (size_t)i) = h;
  *(short8*)(dl + 8 * (size_t)i) = l;
}

// ---------------- bf16x3 MFMA GEMM: C = A @ B^T + bias, K = 512 ----------------
// 64x64 tile, 128 thr = 2 waves (wave owns 32 cols), k-loop unroll 4.
template<int EPI>
__global__ __launch_bounds__(128, 2) void mgemm(
    const ushort_t* __restrict__ Ah, const ushort_t* __restrict__ Al,
    const ushort_t* __restrict__ Bh, const ushort_t* __restrict__ Bl,
    const float* __restrict__ bias, int N, float* __restrict__ out,
    ushort_t* __restrict__ Qh, ushort_t* __restrict__ Ql,
    ushort_t* __restrict__ Kh, ushort_t* __restrict__ Kl,
    ushort_t* __restrict__ Vt)
{
  constexpr int K = DIM_;
  const int lane = threadIdx.x & 63, wid = threadIdx.x >> 6;
  const int m0 = blockIdx.y * 64;
  const int n0 = blockIdx.x * 64 + wid * 32;
  const int arow = lane & 15, agrp = lane >> 4;

  f32x4 acc[4][2];
#pragma unroll
  for (int rt = 0; rt < 4; ++rt)
#pragma unroll
    for (int ct = 0; ct < 2; ++ct) acc[rt][ct] = (f32x4){0.f, 0.f, 0.f, 0.f};

#pragma unroll 4
  for (int ks = 0; ks < K / 32; ++ks) {
    const int ko = ks * 32 + agrp * 8;
    short8 ah[4], al[4];
#pragma unroll
    for (int rt = 0; rt < 4; ++rt) {
      const size_t ao = (size_t)(m0 + rt * 16 + arow) * K + ko;
      ah[rt] = *(const short8*)(Ah + ao);
      al[rt] = *(const short8*)(Al + ao);
    }
    short8 bhf[2], blf[2];
#pragma unroll
    for (int ct = 0; ct < 2; ++ct) {
      const size_t bo = (size_t)(n0 + ct * 16 + arow) * K + ko;
      bhf[ct] = *(const short8*)(Bh + bo);
      blf[ct] = *(const short8*)(Bl + bo);
    }
#pragma unroll
    for (int rt = 0; rt < 4; ++rt)
#pragma unroll
      for (int ct = 0; ct < 2; ++ct) {
        acc[rt][ct] = __builtin_amdgcn_mfma_f32_16x16x32_bf16(ah[rt], bhf[ct], acc[rt][ct], 0, 0, 0);
        acc[rt][ct] = __builtin_amdgcn_mfma_f32_16x16x32_bf16(al[rt], bhf[ct], acc[rt][ct], 0, 0, 0);
        acc[rt][ct] = __builtin_amdgcn_mfma_f32_16x16x32_bf16(ah[rt], blf[ct], acc[rt][ct], 0, 0, 0);
      }
  }

  // C layout: col = lane&15 (n), row = (lane>>4)*4 + reg (m)  [HW-verified]
#pragma unroll
  for (int rt = 0; rt < 4; ++rt) {
#pragma unroll
    for (int ct = 0; ct < 2; ++ct) {
#pragma unroll
      for (int rr = 0; rr < 4; ++rr) {
        const int m = m0 + rt * 16 + agrp * 4 + rr;
        const int n = n0 + ct * 16 + arow;
        float v = acc[rt][ct][rr] + bias[n];
        if (EPI == 0) {
          out[(size_t)m * N + n] = v;
        } else {
          const int b = m >> 11, l = m & (L_ - 1);
          const int which = n >> 9, h = (n >> 6) & (NH_ - 1), d = n & (HD_ - 1);
          const int bh = b * NH_ + h;
          if (which == 0) {
            v *= 0.125f;                      // fold attention scale into Q
            ushort_t hi = bfrne(v);
            float hf = __uint_as_float((unsigned)hi << 16);
            ushort_t lo = bfrne(v - hf);
            const size_t o = ((size_t)bh * L_ + l) * HD_ + d;
            Qh[o] = hi; Ql[o] = lo;
          } else if (which == 1) {
            ushort_t hi = bfrne(v);
            float hf = __uint_as_float((unsigned)hi << 16);
            ushort_t lo = bfrne(v - hf);
            const size_t o = ((size_t)bh * L_ + l) * HD_ + d;
            Kh[o] = hi; Kl[o] = lo;
          } else {
            Vt[((size_t)bh * HD_ + d) * L_ + l] = bfrne(v);
          }
        }
      }
    }
  }
}

// ---- S-GEMM (row-chunked): S[bh][row-row0][key] = Q.K^T bf16x3, LDS-less ----
__global__ __launch_bounds__(256, 4) void sgemm_k(
    const ushort_t* __restrict__ Qh, const ushort_t* __restrict__ Ql,
    const ushort_t* __restrict__ Kh, const ushort_t* __restrict__ Kl,
    float* __restrict__ S, int row0, int CH)
{
  const int lane = threadIdx.x & 63, wid = threadIdx.x >> 6;
  const int bh = blockIdx.z;
  const int m0 = blockIdx.y * 64;               // row offset within chunk
  const int n0 = blockIdx.x * 128 + wid * 32;   // key offset
  const int arow = lane & 15, agrp = lane >> 4;

  short8 kh[2][2], kl[2][2];
#pragma unroll
  for (int kt = 0; kt < 2; ++kt) {
    const size_t ka = ((size_t)bh * L_ + n0 + kt * 16 + arow) * HD_ + agrp * 8;
    kh[kt][0] = *(const short8*)(Kh + ka);
    kh[kt][1] = *(const short8*)(Kh + ka + 32);
    kl[kt][0] = *(const short8*)(Kl + ka);
    kl[kt][1] = *(const short8*)(Kl + ka + 32);
  }

  float* schunk = S + (size_t)bh * CH * L_;
#pragma unroll
  for (int rt = 0; rt < 4; ++rt) {
    const size_t qa = ((size_t)bh * L_ + row0 + m0 + rt * 16 + arow) * HD_ + agrp * 8;
    const short8 qh0 = *(const short8*)(Qh + qa);
    const short8 qh1 = *(const short8*)(Qh + qa + 32);
    const short8 ql0 = *(const short8*)(Ql + qa);
    const short8 ql1 = *(const short8*)(Ql + qa + 32);
#pragma unroll
    for (int kt = 0; kt < 2; ++kt) {
      f32x4 aA = {0.f, 0.f, 0.f, 0.f}, aB = {0.f, 0.f, 0.f, 0.f};
      aA = __builtin_amdgcn_mfma_f32_16x16x32_bf16(qh0, kh[kt][0], aA, 0, 0, 0);
      aB = __builtin_amdgcn_mfma_f32_16x16x32_bf16(qh1, kh[kt][1], aB, 0, 0, 0);
      aA = __builtin_amdgcn_mfma_f32_16x16x32_bf16(ql0, kh[kt][0], aA, 0, 0, 0);
      aB = __builtin_amdgcn_mfma_f32_16x16x32_bf16(ql1, kh[kt][1], aB, 0, 0, 0);
      aA = __builtin_amdgcn_mfma_f32_16x16x32_bf16(qh0, kl[kt][0], aA, 0, 0, 0);
      aB = __builtin_amdgcn_mfma_f32_16x16x32_bf16(qh1, kl[kt][1], aB, 0, 0, 0);
#pragma unroll
      for (int rr = 0; rr < 4; ++rr)
        schunk[(size_t)(m0 + rt * 16 + agrp * 4 + rr) * L_ + n0 + kt * 16 + arow]
            = aA[rr] + aB[rr];
    }
  }
}

// ---- SEL+PV v3: 4 rows/block, 256 thr / 4 waves, 8 blocks/CU (32 waves/CU).
// Same per-row selection math as the r12 champion (scalar S loads, full 24-bit
// bisection). Smaller blocks double per-CU block count -> waves from different
// blocks at different phases share each SIMD (selection VALU overlaps S bursts),
// 4-wave barriers, finer dispatch-tail quantization.  LDS 16.5 KB.
__global__ __launch_bounds__(256, 8) void selpv_k(
    const float* __restrict__ S, const ushort_t* __restrict__ Vt,
    ushort_t* __restrict__ AOh, ushort_t* __restrict__ AOl, int row0, int CH)
{
  __shared__ ushort_t pl[4][2056];   // dense bf16 P; later reused as f32 red buffer
  __shared__ float invs[4];
  float* red = (float*)&pl[0][0];    // 4 KB needed of the 16.4 KB

  const int tid = threadIdx.x, lane = tid & 63, wid = tid >> 6;   // 4 waves
  const int bh = blockIdx.y;
  const int blk = blockIdx.x;               // chunk-local block: 4 rows
  const int arow = lane & 15, agrp = lane >> 4;

  // ---- selection: wave wid owns chunk-row blk*4+wid ----
  {
    const float* srow = S + ((size_t)bh * CH + blk * 4 + wid) * L_;
    unsigned keys[32];
    float mx = -3.0e38f;
#pragma unroll
    for (int t = 0; t < 32; ++t) {
      const float s = srow[lane + 64 * t];
      keys[t] = f2ord(s);
      mx = fmaxf(mx, s);
    }
#pragma unroll
    for (int off = 32; off; off >>= 1) mx = fmaxf(mx, __shfl_xor(mx, off));

    unsigned P = 0;
#pragma unroll 1
    for (int bit = 31; bit >= 8; --bit) {   // 24 bits: 2^8-ulp ties < score noise
      const unsigned cand = P | (1u << bit);
      int c = 0;
#pragma unroll
      for (int t = 0; t < 32; ++t)
        c += (int)__popcll(__ballot(keys[t] >= cand));
      if (c >= TOPK_) P = cand;
    }

    int base = 0;
    float part = 0.f;
#pragma unroll
    for (int t = 0; t < 32; ++t) {
      const bool sel = keys[t] >= P;
      const unsigned long long mb = __ballot(sel);
      const int pos = base + (int)__popcll(mb & ((1ull << lane) - 1ull));
      const float p = (sel && pos < TOPK_) ? __expf(ord2f(keys[t]) - mx) : 0.f;
      pl[wid][lane + 64 * t] = bfrne(p);     // dense bf16 P
      part += p;
      base += (int)__popcll(mb);
    }
#pragma unroll
    for (int off = 32; off; off >>= 1) part += __shfl_xor(part, off);
    if (lane == 0) invs[wid] = 1.f / part;
  }
  __syncthreads();

  // ---- PV: wave wid does keys [wid*512, +512); A-rows 4-15 dup 0-3 ----
  f32x4 o0 = {0.f,0.f,0.f,0.f}, o1 = o0, o2 = o0, o3 = o0;
  {
    const int key00 = wid << 9;
    const size_t vrow = ((size_t)bh * HD_ + arow) * L_;
#pragma unroll 2
    for (int ks = 0; ks < 16; ++ks) {
      const int kb = key00 + ks * 32 + agrp * 8;
      const short8 pa = *(const short8*)&pl[arow & 3][kb];
      const size_t vb0 = vrow + kb;
      const short8 v0 = *(const short8*)(Vt + vb0);
      const short8 v1 = *(const short8*)(Vt + vb0 + 16 * L_);
      const short8 v2 = *(const short8*)(Vt + vb0 + 32 * L_);
      const short8 v3 = *(const short8*)(Vt + vb0 + 48 * L_);
      o0 = __builtin_amdgcn_mfma_f32_16x16x32_bf16(pa, v0, o0, 0, 0, 0);
      o1 = __builtin_amdgcn_mfma_f32_16x16x32_bf16(pa, v1, o1, 0, 0, 0);
      o2 = __builtin_amdgcn_mfma_f32_16x16x32_bf16(pa, v2, o2, 0, 0, 0);
      o3 = __builtin_amdgcn_mfma_f32_16x16x32_bf16(pa, v3, o3, 0, 0, 0);
    }
  }
  __syncthreads();                 // all P reads done; pl reusable as red

  // C rows 0-3 (agrp==0 lanes) hold the 4 real rows; rows 4-15 are duplicates
  if (agrp == 0) {
#pragma unroll
    for (int rr = 0; rr < 4; ++rr) {
      red[wid * 256 + rr * 64 +  0 + arow] = o0[rr];
      red[wid * 256 + rr * 64 + 16 + arow] = o1[rr];
      red[wid * 256 + rr * 64 + 32 + arow] = o2[rr];
      red[wid * 256 + rr * 64 + 48 + arow] = o3[rr];
    }
  }
  __syncthreads();
  {
    const int b = bh >> 3, h = bh & 7;
    const int r = tid >> 6, d = tid & 63;
    float s = 0.f;
#pragma unroll
    for (int w = 0; w < 4; ++w) s += red[w * 256 + r * 64 + d];
    const float sv = s * invs[r];
    const ushort_t hi = bfrne(sv);
    const float hf = __uint_as_float((unsigned)hi << 16);
    const size_t oidx = ((size_t)(b * L_ + row0 + blk * 4 + r)) * DIM_ + h * HD_ + d;
    AOh[oidx] = hi;
    AOl[oidx] = bfrne(sv - hf);
  }
}

// ---------------- Fused fallback (unused unless ws is tiny) ----------------
__global__ __launch_bounds__(1024, 1) void attn_fused_k(
    const ushort_t* __restrict__ Qh, const ushort_t* __restrict__ Ql,
    const ushort_t* __restrict__ Kh, const ushort_t* __restrict__ Kl,
    const ushort_t* __restrict__ Vt,
    ushort_t* __restrict__ AOh, ushort_t* __restrict__ AOl)
{
  __shared__ float sc[16][2052];
  __shared__ float invs[16];

  const int tid = threadIdx.x, lane = tid & 63, wid = tid >> 6;
  const int bh = blockIdx.x >> 7;
  const int l0 = (blockIdx.x & 127) << 4;
  const int arow = lane & 15, agrp = lane >> 4;
  const int key00 = wid << 7;

  const size_t qbase = ((size_t)bh * L_ + l0 + arow) * HD_ + agrp * 8;
  const short8 qh0 = *(const short8*)(Qh + qbase);
  const short8 qh1 = *(const short8*)(Qh + qbase + 32);
  const short8 ql0 = *(const short8*)(Ql + qbase);
  const short8 ql1 = *(const short8*)(Ql + qbase + 32);

  {
#pragma unroll
    for (int t = 0; t < 8; ++t) {
      const int key0 = key00 + t * 16;
      const size_t ka = ((size_t)bh * L_ + key0 + arow) * HD_ + agrp * 8;
      const short8 kh0 = *(const short8*)(Kh + ka);
      const short8 kh1 = *(const short8*)(Kh + ka + 32);
      const short8 kl0 = *(const short8*)(Kl + ka);
      const short8 kl1 = *(const short8*)(Kl + ka + 32);
      f32x4 aA = {0.f, 0.f, 0.f, 0.f}, aB = {0.f, 0.f, 0.f, 0.f};
      aA = __builtin_amdgcn_mfma_f32_16x16x32_bf16(qh0, kh0, aA, 0, 0, 0);
      aB = __builtin_amdgcn_mfma_f32_16x16x32_bf16(qh1, kh1, aB, 0, 0, 0);
      aA = __builtin_amdgcn_mfma_f32_16x16x32_bf16(ql0, kh0, aA, 0, 0, 0);
      aB = __builtin_amdgcn_mfma_f32_16x16x32_bf16(ql1, kh1, aB, 0, 0, 0);
      aA = __builtin_amdgcn_mfma_f32_16x16x32_bf16(qh0, kl0, aA, 0, 0, 0);
      aB = __builtin_amdgcn_mfma_f32_16x16x32_bf16(qh1, kl1, aB, 0, 0, 0);
#pragma unroll
      for (int rr = 0; rr < 4; ++rr)
        sc[agrp * 4 + rr][key0 + arow] = aA[rr] + aB[rr];
    }
  }
  __syncthreads();

  {
    const int r = wid;
    unsigned keys[32];
    float mx = -3.0e38f;
#pragma unroll
    for (int t = 0; t < 32; ++t) {
      const float s = sc[r][lane + 64 * t];
      keys[t] = f2ord(s);
      mx = fmaxf(mx, s);
    }
#pragma unroll
    for (int off = 32; off; off >>= 1) mx = fmaxf(mx, __shfl_xor(mx, off));

    unsigned P = 0;
#pragma unroll 1
    for (int bit = 31; bit >= 8; --bit) {
      const unsigned cand = P | (1u << bit);
      int c = 0;
#pragma unroll
      for (int t = 0; t < 32; ++t)
        c += (int)__popcll(__ballot(keys[t] >= cand));
      if (c >= TOPK_) P = cand;
    }

    int base = 0;
    float part = 0.f;
#pragma unroll
    for (int t = 0; t < 32; ++t) {
      const bool sel = keys[t] >= P;
      const unsigned long long mb = __ballot(sel);
      const int pos = base + (int)__popcll(mb & ((1ull << lane) - 1ull));
      const float p = (sel && pos < TOPK_) ? __expf(ord2f(keys[t]) - mx) : 0.f;
      sc[r][lane + 64 * t] = p;
      part += p;
      base += (int)__popcll(mb);
    }
#pragma unroll
    for (int off = 32; off; off >>= 1) part += __shfl_xor(part, off);
    if (lane == 0) invs[r] = 1.f / part;
  }
  __syncthreads();

  f32x4 o0 = {0.f,0.f,0.f,0.f}, o1 = o0, o2 = o0, o3 = o0;
  {
    const size_t vrow = ((size_t)bh * HD_ + arow) * L_;
#pragma unroll
    for (int ks = 0; ks < 4; ++ks) {
      const int kb = key00 + ks * 32 + agrp * 8;
      float pf[8];
      *(float4*)&pf[0] = *(const float4*)&sc[arow][kb];
      *(float4*)&pf[4] = *(const float4*)&sc[arow][kb + 4];
      short8 pa;
#pragma unroll
      for (int j = 0; j < 8; ++j) pa[j] = (short)bfrne(pf[j]);
      const size_t vb0 = vrow + kb;
      const short8 v0 = *(const short8*)(Vt + vb0);
      const short8 v1 = *(const short8*)(Vt + vb0 + 16 * L_);
      const short8 v2 = *(const short8*)(Vt + vb0 + 32 * L_);
      const short8 v3 = *(const short8*)(Vt + vb0 + 48 * L_);
      o0 = __builtin_amdgcn_mfma_f32_16x16x32_bf16(pa, v0, o0, 0, 0, 0);
      o1 = __builtin_amdgcn_mfma_f32_16x16x32_bf16(pa, v1, o1, 0, 0, 0);
      o2 = __builtin_amdgcn_mfma_f32_16x16x32_bf16(pa, v2, o2, 0, 0, 0);
      o3 = __builtin_amdgcn_mfma_f32_16x16x32_bf16(pa, v3, o3, 0, 0, 0);
    }
  }
  __syncthreads();

  float* red = &sc[0][0];
  {
#pragma unroll
    for (int rr = 0; rr < 4; ++rr) {
      const int row = agrp * 4 + rr;
      red[wid * 1024 + row * 64 +  0 + arow] = o0[rr];
      red[wid * 1024 + row * 64 + 16 + arow] = o1[rr];
      red[wid * 1024 + row * 64 + 32 + arow] = o2[rr];
      red[wid * 1024 + row * 64 + 48 + arow] = o3[rr];
    }
  }
  __syncthreads();
  {
    const int b = bh >> 3, h = bh & 7;
    const int r = tid >> 6, d = tid & 63;
    float s = 0.f;
#pragma unroll
    for (int w = 0; w < 16; ++w) s += red[w * 1024 + tid];
    const float sv = s * invs[r];
    const ushort_t hi = bfrne(sv);
    const float hf = __uint_as_float((unsigned)hi << 16);
    const size_t oidx = ((size_t)(b * L_ + l0 + r)) * DIM_ + h * HD_ + d;
    AOh[oidx] = hi;
    AOl[oidx] = bfrne(sv - hf);
  }
}

extern "C" void kernel_launch(void* const* d_in, const int* in_sizes, int n_in,
                              void* d_out, int out_size, void* d_ws, size_t ws_size,
                              hipStream_t stream) {
  const float* x     = (const float*)d_in[0];
  const float* w_qkv = (const float*)d_in[1];
  const float* b_qkv = (const float*)d_in[2];
  const float* w_out = (const float*)d_in[3];
  const float* b_out = (const float*)d_in[4];
  float* out = (float*)d_out;

  const size_t NE  = (size_t)B_ * NH_ * L_ * HD_;  // 2,097,152 (= x elems = AO elems)
  const size_t NWQ = (size_t)3 * DIM_ * DIM_;      //   786,432
  const size_t NWO = (size_t)DIM_ * DIM_;          //   262,144

  // layout (ushorts): QKVT | AOh AOl | woh wol | [xh xl wqh wql]  <- S reuses []
  ushort_t* us  = (ushort_t*)d_ws;
  ushort_t* Qh  = us;
  ushort_t* Ql  = Qh + NE;
  ushort_t* Kh  = Ql + NE;
  ushort_t* Kl  = Kh + NE;
  ushort_t* Vt  = Kl + NE;
  ushort_t* AOh = Vt + NE;
  ushort_t* AOl = AOh + NE;
  ushort_t* woh = AOl + NE;
  ushort_t* wol = woh + NWO;
  ushort_t* xh  = wol + NWO;        // dead after mgemm<1>; S chunk starts here
  ushort_t* xl  = xh + NE;
  ushort_t* wqh = xl + NE;
  ushort_t* wql = wqh + NWQ;
  float*    S   = (float*)xh;

  const size_t sOffB   = (size_t)(7 * NE + 2 * NWO) * sizeof(ushort_t); // 30.4 MB
  const size_t perRowB = (size_t)B_ * NH_ * L_ * sizeof(float);          // 131072 B

  int CH = 0;
  const int cands[6] = {1024, 512, 2048, 256, 128, 64};
  for (int i = 0; i < 6; ++i)
    if (sOffB + (size_t)cands[i] * perRowB <= ws_size) { CH = cands[i]; break; }

  split_k<<<(int)((NE  / 8 + 255) / 256), 256, 0, stream>>>(x,     xh,  xl,  (int)(NE  / 8));
  split_k<<<(int)((NWQ / 8 + 255) / 256), 256, 0, stream>>>(w_qkv, wqh, wql, (int)(NWQ / 8));
  split_k<<<(int)((NWO / 8 + 255) / 256), 256, 0, stream>>>(w_out, woh, wol, (int)(NWO / 8));

  // QKV: [4096 x 1536] = x @ w_qkv^T, scatter epilogue
  mgemm<1><<<dim3((3 * DIM_) / 64, (B_ * L_) / 64), 128, 0, stream>>>(
      xh, xl, wqh, wql, b_qkv, 3 * DIM_, nullptr, Qh, Ql, Kh, Kl, Vt);

  if (CH) {
    for (int row0 = 0; row0 < L_; row0 += CH) {
      sgemm_k<<<dim3(L_ / 128, CH / 64, B_ * NH_), 256, 0, stream>>>(
          Qh, Ql, Kh, Kl, S, row0, CH);
      selpv_k<<<dim3(CH / 4, B_ * NH_), 256, 0, stream>>>(S, Vt, AOh, AOl, row0, CH);
    }
  } else {
    attn_fused_k<<<dim3(B_ * NH_ * (L_ / 16)), 1024, 0, stream>>>(
        Qh, Ql, Kh, Kl, Vt, AOh, AOl);
  }

  // OUT: [4096 x 512] = AO @ w_out^T + b_out
  mgemm<0><<<dim3(DIM_ / 64, (B_ * L_) / 64), 128, 0, stream>>>(
      AOh, AOl, woh, wol, b_out, DIM_, out, nullptr, nullptr, nullptr, nullptr, nullptr);
}

// Round 20
// 385.071 us; speedup vs baseline: 1.2894x; 1.2894x over previous
//
#include <hip/hip_runtime.h>

#define B_ 2
#define L_ 2048
#define DIM_ 512
#define NH_ 8
#define HD_ 64
#define TOPK_ 512

typedef __attribute__((ext_vector_type(8))) short short8;
typedef __attribute__((ext_vector_type(4))) float f32x4;
typedef unsigned short ushort_t;

__device__ __forceinline__ unsigned f2ord(float f) {
  unsigned u = __float_as_uint(f);
  return (u >> 31) ? ~u : (u | 0x80000000u);
}
__device__ __forceinline__ float ord2f(unsigned k) {
  unsigned u = (k >> 31) ? (k ^ 0x80000000u) : ~k;
  return __uint_as_float(u);
}
// f32 -> bf16 bits, round-to-nearest-even
__device__ __forceinline__ ushort_t bfrne(float f) {
  unsigned u = __float_as_uint(f);
  return (ushort_t)((u + 0x7FFFu + ((u >> 16) & 1u)) >> 16);
}

// ---------------- split f32 -> bf16 hi/lo panels (8 elems/thread) ----------------
__global__ __launch_bounds__(256) void split_k(
    const float* __restrict__ src, ushort_t* __restrict__ dh,
    ushort_t* __restrict__ dl, int n8)
{
  const int i = blockIdx.x * 256 + threadIdx.x;
  if (i >= n8) return;
  const float4 a = ((const float4*)src)[2 * i];
  const float4 b = ((const float4*)src)[2 * i + 1];
  float f[8] = {a.x, a.y, a.z, a.w, b.x, b.y, b.z, b.w};
  short8 h, l;
#pragma unroll
  for (int j = 0; j < 8; ++j) {
    const ushort_t hi = bfrne(f[j]);
    const float hf = __uint_as_float((unsigned)hi << 16);
    h[j] = (short)hi;
    l[j] = (short)bfrne(f[j] - hf);
  }
  *(short8*)(dh + 8 * (size_t)i) = h;
  *(short8*)(dl + 8 * (size_t)i) = l;
}

// ---------------- bf16x3 MFMA GEMM: C = A @ B^T + bias, K = 512 ----------------
// 64x64 tile, 128 thr = 2 waves (wave owns 32 cols), k-loop unroll 4.
template<int EPI>
__global__ __launch_bounds__(128, 2) void mgemm(
    const ushort_t* __restrict__ Ah, const ushort_t* __restrict__ Al,
    const ushort_t* __restrict__ Bh, const ushort_t* __restrict__ Bl,
    const float* __restrict__ bias, int N, float* __restrict__ out,
    ushort_t* __restrict__ Qh, ushort_t* __restrict__ Ql,
    ushort_t* __restrict__ Kh, ushort_t* __restrict__ Kl,
    ushort_t* __restrict__ Vt)
{
  constexpr int K = DIM_;
  const int lane = threadIdx.x & 63, wid = threadIdx.x >> 6;
  const int m0 = blockIdx.y * 64;
  const int n0 = blockIdx.x * 64 + wid * 32;
  const int arow = lane & 15, agrp = lane >> 4;

  f32x4 acc[4][2];
#pragma unroll
  for (int rt = 0; rt < 4; ++rt)
#pragma unroll
    for (int ct = 0; ct < 2; ++ct) acc[rt][ct] = (f32x4){0.f, 0.f, 0.f, 0.f};

#pragma unroll 4
  for (int ks = 0; ks < K / 32; ++ks) {
    const int ko = ks * 32 + agrp * 8;
    short8 ah[4], al[4];
#pragma unroll
    for (int rt = 0; rt < 4; ++rt) {
      const size_t ao = (size_t)(m0 + rt * 16 + arow) * K + ko;
      ah[rt] = *(const short8*)(Ah + ao);
      al[rt] = *(const short8*)(Al + ao);
    }
    short8 bhf[2], blf[2];
#pragma unroll
    for (int ct = 0; ct < 2; ++ct) {
      const size_t bo = (size_t)(n0 + ct * 16 + arow) * K + ko;
      bhf[ct] = *(const short8*)(Bh + bo);
      blf[ct] = *(const short8*)(Bl + bo);
    }
#pragma unroll
    for (int rt = 0; rt < 4; ++rt)
#pragma unroll
      for (int ct = 0; ct < 2; ++ct) {
        acc[rt][ct] = __builtin_amdgcn_mfma_f32_16x16x32_bf16(ah[rt], bhf[ct], acc[rt][ct], 0, 0, 0);
        acc[rt][ct] = __builtin_amdgcn_mfma_f32_16x16x32_bf16(al[rt], bhf[ct], acc[rt][ct], 0, 0, 0);
        acc[rt][ct] = __builtin_amdgcn_mfma_f32_16x16x32_bf16(ah[rt], blf[ct], acc[rt][ct], 0, 0, 0);
      }
  }

  // C layout: col = lane&15 (n), row = (lane>>4)*4 + reg (m)  [HW-verified]
#pragma unroll
  for (int rt = 0; rt < 4; ++rt) {
#pragma unroll
    for (int ct = 0; ct < 2; ++ct) {
#pragma unroll
      for (int rr = 0; rr < 4; ++rr) {
        const int m = m0 + rt * 16 + agrp * 4 + rr;
        const int n = n0 + ct * 16 + arow;
        float v = acc[rt][ct][rr] + bias[n];
        if (EPI == 0) {
          out[(size_t)m * N + n] = v;
        } else {
          const int b = m >> 11, l = m & (L_ - 1);
          const int which = n >> 9, h = (n >> 6) & (NH_ - 1), d = n & (HD_ - 1);
          const int bh = b * NH_ + h;
          if (which == 0) {
            v *= 0.125f;                      // fold attention scale into Q
            ushort_t hi = bfrne(v);
            float hf = __uint_as_float((unsigned)hi << 16);
            ushort_t lo = bfrne(v - hf);
            const size_t o = ((size_t)bh * L_ + l) * HD_ + d;
            Qh[o] = hi; Ql[o] = lo;
          } else if (which == 1) {
            ushort_t hi = bfrne(v);
            float hf = __uint_as_float((unsigned)hi << 16);
            ushort_t lo = bfrne(v - hf);
            const size_t o = ((size_t)bh * L_ + l) * HD_ + d;
            Kh[o] = hi; Kl[o] = lo;
          } else {
            Vt[((size_t)bh * HD_ + d) * L_ + l] = bfrne(v);
          }
        }
      }
    }
  }
}

// ---- S-GEMM (row-chunked): S[bh][row-row0][key] = Q.K^T bf16x3, LDS-less ----
__global__ __launch_bounds__(256, 4) void sgemm_k(
    const ushort_t* __restrict__ Qh, const ushort_t* __restrict__ Ql,
    const ushort_t* __restrict__ Kh, const ushort_t* __restrict__ Kl,
    float* __restrict__ S, int row0, int CH)
{
  const int lane = threadIdx.x & 63, wid = threadIdx.x >> 6;
  const int bh = blockIdx.z;
  const int m0 = blockIdx.y * 64;               // row offset within chunk
  const int n0 = blockIdx.x * 128 + wid * 32;   // key offset
  const int arow = lane & 15, agrp = lane >> 4;

  short8 kh[2][2], kl[2][2];
#pragma unroll
  for (int kt = 0; kt < 2; ++kt) {
    const size_t ka = ((size_t)bh * L_ + n0 + kt * 16 + arow) * HD_ + agrp * 8;
    kh[kt][0] = *(const short8*)(Kh + ka);
    kh[kt][1] = *(const short8*)(Kh + ka + 32);
    kl[kt][0] = *(const short8*)(Kl + ka);
    kl[kt][1] = *(const short8*)(Kl + ka + 32);
  }

  float* schunk = S + (size_t)bh * CH * L_;
#pragma unroll
  for (int rt = 0; rt < 4; ++rt) {
    const size_t qa = ((size_t)bh * L_ + row0 + m0 + rt * 16 + arow) * HD_ + agrp * 8;
    const short8 qh0 = *(const short8*)(Qh + qa);
    const short8 qh1 = *(const short8*)(Qh + qa + 32);
    const short8 ql0 = *(const short8*)(Ql + qa);
    const short8 ql1 = *(const short8*)(Ql + qa + 32);
#pragma unroll
    for (int kt = 0; kt < 2; ++kt) {
      f32x4 aA = {0.f, 0.f, 0.f, 0.f}, aB = {0.f, 0.f, 0.f, 0.f};
      aA = __builtin_amdgcn_mfma_f32_16x16x32_bf16(qh0, kh[kt][0], aA, 0, 0, 0);
      aB = __builtin_amdgcn_mfma_f32_16x16x32_bf16(qh1, kh[kt][1], aB, 0, 0, 0);
      aA = __builtin_amdgcn_mfma_f32_16x16x32_bf16(ql0, kh[kt][0], aA, 0, 0, 0);
      aB = __builtin_amdgcn_mfma_f32_16x16x32_bf16(ql1, kh[kt][1], aB, 0, 0, 0);
      aA = __builtin_amdgcn_mfma_f32_16x16x32_bf16(qh0, kl[kt][0], aA, 0, 0, 0);
      aB = __builtin_amdgcn_mfma_f32_16x16x32_bf16(qh1, kl[kt][1], aB, 0, 0, 0);
#pragma unroll
      for (int rr = 0; rr < 4; ++rr)
        schunk[(size_t)(m0 + rt * 16 + agrp * 4 + rr) * L_ + n0 + kt * 16 + arow]
            = aA[rr] + aB[rr];
    }
  }
}

// ---- SEL+PV (round-12/18 champion): 8 rows/block, 512 thr / 8 waves.
// Scalar S loads (32 outstanding dwords/wave = max MLP), full 24-bit bisection
// (no data-dependent branch), LDS overlay (red reuses pl) = 32.9 KB, 4 blocks/CU.
__global__ __launch_bounds__(512, 8) void selpv_k(
    const float* __restrict__ S, const ushort_t* __restrict__ Vt,
    ushort_t* __restrict__ AOh, ushort_t* __restrict__ AOl, int row0, int CH)
{
  __shared__ ushort_t pl[8][2056];   // dense bf16 P; later reused as f32 red buffer
  __shared__ float invs[8];
  float* red = (float*)&pl[0][0];    // 16 KB needed of the 32.9 KB

  const int tid = threadIdx.x, lane = tid & 63, wid = tid >> 6;   // 8 waves
  const int bh = blockIdx.y;
  const int blk = blockIdx.x;               // chunk-local block: 8 rows
  const int arow = lane & 15, agrp = lane >> 4;

  // ---- selection: wave wid owns chunk-row blk*8+wid ----
  {
    const float* srow = S + ((size_t)bh * CH + blk * 8 + wid) * L_;
    unsigned keys[32];
    float mx = -3.0e38f;
#pragma unroll
    for (int t = 0; t < 32; ++t) {
      const float s = srow[lane + 64 * t];
      keys[t] = f2ord(s);
      mx = fmaxf(mx, s);
    }
#pragma unroll
    for (int off = 32; off; off >>= 1) mx = fmaxf(mx, __shfl_xor(mx, off));

    unsigned P = 0;
#pragma unroll 1
    for (int bit = 31; bit >= 8; --bit) {   // 24 bits: 2^8-ulp ties < score noise
      const unsigned cand = P | (1u << bit);
      int c = 0;
#pragma unroll
      for (int t = 0; t < 32; ++t)
        c += (int)__popcll(__ballot(keys[t] >= cand));
      if (c >= TOPK_) P = cand;
    }

    int base = 0;
    float part = 0.f;
#pragma unroll
    for (int t = 0; t < 32; ++t) {
      const bool sel = keys[t] >= P;
      const unsigned long long mb = __ballot(sel);
      const int pos = base + (int)__popcll(mb & ((1ull << lane) - 1ull));
      const float p = (sel && pos < TOPK_) ? __expf(ord2f(keys[t]) - mx) : 0.f;
      pl[wid][lane + 64 * t] = bfrne(p);     // dense bf16 P
      part += p;
      base += (int)__popcll(mb);
    }
#pragma unroll
    for (int off = 32; off; off >>= 1) part += __shfl_xor(part, off);
    if (lane == 0) invs[wid] = 1.f / part;
  }
  __syncthreads();

  // ---- PV: wave wid does keys [wid*256, +256); A-rows 8-15 dup 0-7 ----
  f32x4 o0 = {0.f,0.f,0.f,0.f}, o1 = o0, o2 = o0, o3 = o0;
  {
    const int key00 = wid << 8;
    const size_t vrow = ((size_t)bh * HD_ + arow) * L_;
#pragma unroll 2
    for (int ks = 0; ks < 8; ++ks) {
      const int kb = key00 + ks * 32 + agrp * 8;
      const short8 pa = *(const short8*)&pl[arow & 7][kb];
      const size_t vb0 = vrow + kb;
      const short8 v0 = *(const short8*)(Vt + vb0);
      const short8 v1 = *(const short8*)(Vt + vb0 + 16 * L_);
      const short8 v2 = *(const short8*)(Vt + vb0 + 32 * L_);
      const short8 v3 = *(const short8*)(Vt + vb0 + 48 * L_);
      o0 = __builtin_amdgcn_mfma_f32_16x16x32_bf16(pa, v0, o0, 0, 0, 0);
      o1 = __builtin_amdgcn_mfma_f32_16x16x32_bf16(pa, v1, o1, 0, 0, 0);
      o2 = __builtin_amdgcn_mfma_f32_16x16x32_bf16(pa, v2, o2, 0, 0, 0);
      o3 = __builtin_amdgcn_mfma_f32_16x16x32_bf16(pa, v3, o3, 0, 0, 0);
    }
  }
  __syncthreads();                 // all P reads done; pl reusable as red

  if (agrp < 2) {
#pragma unroll
    for (int rr = 0; rr < 4; ++rr) {
      const int row = agrp * 4 + rr;
      red[wid * 512 + row * 64 +  0 + arow] = o0[rr];
      red[wid * 512 + row * 64 + 16 + arow] = o1[rr];
      red[wid * 512 + row * 64 + 32 + arow] = o2[rr];
      red[wid * 512 + row * 64 + 48 + arow] = o3[rr];
    }
  }
  __syncthreads();
  {
    const int b = bh >> 3, h = bh & 7;
    const int r = tid >> 6, d = tid & 63;
    float s = 0.f;
#pragma unroll
    for (int w = 0; w < 8; ++w) s += red[w * 512 + r * 64 + d];
    const float sv = s * invs[r];
    const ushort_t hi = bfrne(sv);
    const float hf = __uint_as_float((unsigned)hi << 16);
    const size_t oidx = ((size_t)(b * L_ + row0 + blk * 8 + r)) * DIM_ + h * HD_ + d;
    AOh[oidx] = hi;
    AOl[oidx] = bfrne(sv - hf);
  }
}

// ---------------- Fused fallback (unused unless ws is tiny) ----------------
__global__ __launch_bounds__(1024, 1) void attn_fused_k(
    const ushort_t* __restrict__ Qh, const ushort_t* __restrict__ Ql,
    const ushort_t* __restrict__ Kh, const ushort_t* __restrict__ Kl,
    const ushort_t* __restrict__ Vt,
    ushort_t* __restrict__ AOh, ushort_t* __restrict__ AOl)
{
  __shared__ float sc[16][2052];
  __shared__ float invs[16];

  const int tid = threadIdx.x, lane = tid & 63, wid = tid >> 6;
  const int bh = blockIdx.x >> 7;
  const int l0 = (blockIdx.x & 127) << 4;
  const int arow = lane & 15, agrp = lane >> 4;
  const int key00 = wid << 7;

  const size_t qbase = ((size_t)bh * L_ + l0 + arow) * HD_ + agrp * 8;
  const short8 qh0 = *(const short8*)(Qh + qbase);
  const short8 qh1 = *(const short8*)(Qh + qbase + 32);
  const short8 ql0 = *(const short8*)(Ql + qbase);
  const short8 ql1 = *(const short8*)(Ql + qbase + 32);

  {
#pragma unroll
    for (int t = 0; t < 8; ++t) {
      const int key0 = key00 + t * 16;
      const size_t ka = ((size_t)bh * L_ + key0 + arow) * HD_ + agrp * 8;
      const short8 kh0 = *(const short8*)(Kh + ka);
      const short8 kh1 = *(const short8*)(Kh + ka + 32);
      const short8 kl0 = *(const short8*)(Kl + ka);
      const short8 kl1 = *(const short8*)(Kl + ka + 32);
      f32x4 aA = {0.f, 0.f, 0.f, 0.f}, aB = {0.f, 0.f, 0.f, 0.f};
      aA = __builtin_amdgcn_mfma_f32_16x16x32_bf16(qh0, kh0, aA, 0, 0, 0);
      aB = __builtin_amdgcn_mfma_f32_16x16x32_bf16(qh1, kh1, aB, 0, 0, 0);
      aA = __builtin_amdgcn_mfma_f32_16x16x32_bf16(ql0, kh0, aA, 0, 0, 0);
      aB = __builtin_amdgcn_mfma_f32_16x16x32_bf16(ql1, kh1, aB, 0, 0, 0);
      aA = __builtin_amdgcn_mfma_f32_16x16x32_bf16(qh0, kl0, aA, 0, 0, 0);
      aB = __builtin_amdgcn_mfma_f32_16x16x32_bf16(qh1, kl1, aB, 0, 0, 0);
#pragma unroll
      for (int rr = 0; rr < 4; ++rr)
        sc[agrp * 4 + rr][key0 + arow] = aA[rr] + aB[rr];
    }
  }
  __syncthreads();

  {
    const int r = wid;
    unsigned keys[32];
    float mx = -3.0e38f;
#pragma unroll
    for (int t = 0; t < 32; ++t) {
      const float s = sc[r][lane + 64 * t];
      keys[t] = f2ord(s);
      mx = fmaxf(mx, s);
    }
#pragma unroll
    for (int off = 32; off; off >>= 1) mx = fmaxf(mx, __shfl_xor(mx, off));

    unsigned P = 0;
#pragma unroll 1
    for (int bit = 31; bit >= 8; --bit) {
      const unsigned cand = P | (1u << bit);
      int c = 0;
#pragma unroll
      for (int t = 0; t < 32; ++t)
        c += (int)__popcll(__ballot(keys[t] >= cand));
      if (c >= TOPK_) P = cand;
    }

    int base = 0;
    float part = 0.f;
#pragma unroll
    for (int t = 0; t < 32; ++t) {
      const bool sel = keys[t] >= P;
      const unsigned long long mb = __ballot(sel);
      const int pos = base + (int)__popcll(mb & ((1ull << lane) - 1ull));
      const float p = (sel && pos < TOPK_) ? __expf(ord2f(keys[t]) - mx) : 0.f;
      sc[r][lane + 64 * t] = p;
      part += p;
      base += (int)__popcll(mb);
    }
#pragma unroll
    for (int off = 32; off; off >>= 1) part += __shfl_xor(part, off);
    if (lane == 0) invs[r] = 1.f / part;
  }
  __syncthreads();

  f32x4 o0 = {0.f,0.f,0.f,0.f}, o1 = o0, o2 = o0, o3 = o0;
  {
    const size_t vrow = ((size_t)bh * HD_ + arow) * L_;
#pragma unroll
    for (int ks = 0; ks < 4; ++ks) {
      const int kb = key00 + ks * 32 + agrp * 8;
      float pf[8];
      *(float4*)&pf[0] = *(const float4*)&sc[arow][kb];
      *(float4*)&pf[4] = *(const float4*)&sc[arow][kb + 4];
      short8 pa;
#pragma unroll
      for (int j = 0; j < 8; ++j) pa[j] = (short)bfrne(pf[j]);
      const size_t vb0 = vrow + kb;
      const short8 v0 = *(const short8*)(Vt + vb0);
      const short8 v1 = *(const short8*)(Vt + vb0 + 16 * L_);
      const short8 v2 = *(const short8*)(Vt + vb0 + 32 * L_);
      const short8 v3 = *(const short8*)(Vt + vb0 + 48 * L_);
      o0 = __builtin_amdgcn_mfma_f32_16x16x32_bf16(pa, v0, o0, 0, 0, 0);
      o1 = __builtin_amdgcn_mfma_f32_16x16x32_bf16(pa, v1, o1, 0, 0, 0);
      o2 = __builtin_amdgcn_mfma_f32_16x16x32_bf16(pa, v2, o2, 0, 0, 0);
      o3 = __builtin_amdgcn_mfma_f32_16x16x32_bf16(pa, v3, o3, 0, 0, 0);
    }
  }
  __syncthreads();

  float* red = &sc[0][0];
  {
#pragma unroll
    for (int rr = 0; rr < 4; ++rr) {
      const int row = agrp * 4 + rr;
      red[wid * 1024 + row * 64 +  0 + arow] = o0[rr];
      red[wid * 1024 + row * 64 + 16 + arow] = o1[rr];
      red[wid * 1024 + row * 64 + 32 + arow] = o2[rr];
      red[wid * 1024 + row * 64 + 48 + arow] = o3[rr];
    }
  }
  __syncthreads();
  {
    const int b = bh >> 3, h = bh & 7;
    const int r = tid >> 6, d = tid & 63;
    float s = 0.f;
#pragma unroll
    for (int w = 0; w < 16; ++w) s += red[w * 1024 + tid];
    const float sv = s * invs[r];
    const ushort_t hi = bfrne(sv);
    const float hf = __uint_as_float((unsigned)hi << 16);
    const size_t oidx = ((size_t)(b * L_ + l0 + r)) * DIM_ + h * HD_ + d;
    AOh[oidx] = hi;
    AOl[oidx] = bfrne(sv - hf);
  }
}

extern "C" void kernel_launch(void* const* d_in, const int* in_sizes, int n_in,
                              void* d_out, int out_size, void* d_ws, size_t ws_size,
                              hipStream_t stream) {
  const float* x     = (const float*)d_in[0];
  const float* w_qkv = (const float*)d_in[1];
  const float* b_qkv = (const float*)d_in[2];
  const float* w_out = (const float*)d_in[3];
  const float* b_out = (const float*)d_in[4];
  float* out = (float*)d_out;

  const size_t NE  = (size_t)B_ * NH_ * L_ * HD_;  // 2,097,152 (= x elems = AO elems)
  const size_t NWQ = (size_t)3 * DIM_ * DIM_;      //   786,432
  const size_t NWO = (size_t)DIM_ * DIM_;          //   262,144

  // layout (ushorts): QKVT | AOh AOl | woh wol | [xh xl wqh wql]  <- S reuses []
  ushort_t* us  = (ushort_t*)d_ws;
  ushort_t* Qh  = us;
  ushort_t* Ql  = Qh + NE;
  ushort_t* Kh  = Ql + NE;
  ushort_t* Kl  = Kh + NE;
  ushort_t* Vt  = Kl + NE;
  ushort_t* AOh = Vt + NE;
  ushort_t* AOl = AOh + NE;
  ushort_t* woh = AOl + NE;
  ushort_t* wol = woh + NWO;
  ushort_t* xh  = wol + NWO;        // dead after mgemm<1>; S chunk starts here
  ushort_t* xl  = xh + NE;
  ushort_t* wqh = xl + NE;
  ushort_t* wql = wqh + NWQ;
  float*    S   = (float*)xh;

  const size_t sOffB   = (size_t)(7 * NE + 2 * NWO) * sizeof(ushort_t); // 30.4 MB
  const size_t perRowB = (size_t)B_ * NH_ * L_ * sizeof(float);          // 131072 B

  int CH = 0;
  const int cands[6] = {1024, 512, 2048, 256, 128, 64};
  for (int i = 0; i < 6; ++i)
    if (sOffB + (size_t)cands[i] * perRowB <= ws_size) { CH = cands[i]; break; }

  split_k<<<(int)((NE  / 8 + 255) / 256), 256, 0, stream>>>(x,     xh,  xl,  (int)(NE  / 8));
  split_k<<<(int)((NWQ / 8 + 255) / 256), 256, 0, stream>>>(w_qkv, wqh, wql, (int)(NWQ / 8));
  split_k<<<(int)((NWO / 8 + 255) / 256), 256, 0, stream>>>(w_out, woh, wol, (int)(NWO / 8));

  // QKV: [4096 x 1536] = x @ w_qkv^T, scatter epilogue
  mgemm<1><<<dim3((3 * DIM_) / 64, (B_ * L_) / 64), 128, 0, stream>>>(
      xh, xl, wqh, wql, b_qkv, 3 * DIM_, nullptr, Qh, Ql, Kh, Kl, Vt);

  if (CH) {
    for (int row0 = 0; row0 < L_; row0 += CH) {
      sgemm_k<<<dim3(L_ / 128, CH / 64, B_ * NH_), 256, 0, stream>>>(
          Qh, Ql, Kh, Kl, S, row0, CH);
      selpv_k<<<dim3(CH / 8, B_ * NH_), 512, 0, stream>>>(S, Vt, AOh, AOl, row0, CH);
    }
  } else {
    attn_fused_k<<<dim3(B_ * NH_ * (L_ / 16)), 1024, 0, stream>>>(
        Qh, Ql, Kh, Kl, Vt, AOh, AOl);
  }

  // OUT: [4096 x 512] = AO @ w_out^T + b_out
  mgemm<0><<<dim3(DIM_ / 64, (B_ * L_) / 64), 128, 0, stream>>>(
      AOh, AOl, woh, wol, b_out, DIM_, out, nullptr, nullptr, nullptr, nullptr, nullptr);
}